// Round 5
// baseline (1141.126 us; speedup 1.0000x reference)
//
#include <hip/hip_runtime.h>

#define RNN_B 64
#define RNN_T 1024
#define RNN_D 256
#define RNN_H 256

typedef __attribute__((ext_vector_type(8))) short bf16x8;
typedef __attribute__((ext_vector_type(4))) float f32x4;

__device__ __forceinline__ unsigned short f32_to_bf16_rne(float f) {
  unsigned u = __builtin_bit_cast(unsigned, f);
  u += 0x7fffu + ((u >> 16) & 1u);
  return (unsigned short)(u >> 16);
}

// branch-free tanh: 1 - 2/(exp(2x)+1); exact at +/-inf, ~1e-6 abs err
__device__ __forceinline__ float tanh_fast(float x) {
  const float t = __expf(2.0f * x);
  const float r = __builtin_amdgcn_rcpf(t + 1.0f);
  return fmaf(-2.0f, r, 1.0f);
}

// swizzled u16 index of h[batch][col] in an 8KB LDS buffer.
// XOR of (batch&7)<<4 on the byte offset spreads rows across 16B bank-slots.
__device__ __forceinline__ int hidx(int batch, int col) {
  return (batch * 512 + ((col * 2) ^ ((batch & 7) << 4))) >> 1;
}

__device__ __forceinline__ void wg_barrier_lds_only() {
  // drain LDS ops only; deliberately NOT vmcnt -> global xp prefetch and h
  // stores stay in flight across steps (avoids __syncthreads' vmcnt(0) drain)
  asm volatile("s_waitcnt lgkmcnt(0)" ::: "memory");
  __builtin_amdgcn_sched_barrier(0);
  __builtin_amdgcn_s_barrier();
  __builtin_amdgcn_sched_barrier(0);
}

// ---------------------------------------------------------------------------
// Kernel 1: xp[b,t,:] = x[b,t,:] @ Wx + b  (into the hs region of out) — f32
// ---------------------------------------------------------------------------
__global__ __launch_bounds__(256) void xp_gemm_kernel(
    const float* __restrict__ x, const float* __restrict__ Wx,
    const float* __restrict__ bias, float* __restrict__ xp) {
  __shared__ float xs[8][RNN_D];
  const int j = threadIdx.x;
  const size_t row0 = (size_t)blockIdx.x * 8;

  const float4* xg = reinterpret_cast<const float4*>(x + row0 * RNN_D);
  float4* xsv = reinterpret_cast<float4*>(&xs[0][0]);
  xsv[j] = xg[j];
  xsv[j + 256] = xg[j + 256];
  __syncthreads();

  const float bj = bias[j];
  float acc[8];
#pragma unroll
  for (int r = 0; r < 8; ++r) acc[r] = bj;

  for (int k = 0; k < RNN_D; k += 4) {
    const float w0 = Wx[(size_t)(k + 0) * RNN_H + j];
    const float w1 = Wx[(size_t)(k + 1) * RNN_H + j];
    const float w2 = Wx[(size_t)(k + 2) * RNN_H + j];
    const float w3 = Wx[(size_t)(k + 3) * RNN_H + j];
#pragma unroll
    for (int r = 0; r < 8; ++r) {
      const float4 xv = *reinterpret_cast<const float4*>(&xs[r][k]);
      acc[r] = fmaf(xv.x, w0, acc[r]);
      acc[r] = fmaf(xv.y, w1, acc[r]);
      acc[r] = fmaf(xv.z, w2, acc[r]);
      acc[r] = fmaf(xv.w, w3, acc[r]);
    }
  }
#pragma unroll
  for (int r = 0; r < 8; ++r) xp[(row0 + r) * RNN_H + j] = acc[r];
}

// ---------------------------------------------------------------------------
// One recurrence step. Swapped-operand MFMA: S^T = Wh^T (A') x h^T (B').
// 8 waves; wave wid owns outcol tiles nt = 2*wid + i (i in {0,1}).
// Lane roles per tile (16x16x32):
//   A'-frag (Wh^T): m = lane&15 -> outcol = 16*nt + m; k = (lane>>4)*8+j (VGPR)
//   B'-frag (h^T):  n = lane&15 -> batch;  k likewise  (LDS b128, swizzled)
//   C/D:            batch = lane&15, outcol = 16*nt + (lane>>4)*4 + r
// -> each thread owns 4 CONSECUTIVE outcols for one batch: float4 global
//    ld/st, packed b64 LDS writes via v_cvt_pk_bf16_f32.
// acc seeded with xp (C-in) -> no separate add.
// ---------------------------------------------------------------------------
template <int RD, int TOFF>
__device__ __forceinline__ void rnn_step(
    unsigned short (&hb)[2][16 * 256], const bf16x8 (&wfrag)[2][8],
    f32x4 (&xc)[2], f32x4 (&xn)[2],
    const float* const (&xp_ld)[2], float* const (&h_st)[2],
    float* const (&hl_st)[2], bool last, int lrow, int lq, int wid) {
  // 1) prefetch xp for the NEXT step (consumed after the next barrier)
#pragma unroll
  for (int i = 0; i < 2; ++i)
    xn[i] = *reinterpret_cast<const f32x4*>(&xp_ld[i][TOFF * RNN_H]);

  // 2) B'-fragments of h from LDS (8 x ds_read_b128, swizzled)
  bf16x8 hf[8];
#pragma unroll
  for (int kc = 0; kc < 8; ++kc) {
    const int off = (lrow * 512 + ((kc * 64 + lq * 16) ^ ((lrow & 7) << 4))) >> 1;
    hf[kc] = *reinterpret_cast<const bf16x8*>(&hb[RD][off]);
  }

  // 3) MFMA chain, acc seeded with xp
  f32x4 acc[2] = {xc[0], xc[1]};
  __builtin_amdgcn_s_setprio(1);
#pragma unroll
  for (int kc = 0; kc < 8; ++kc)
#pragma unroll
    for (int i = 0; i < 2; ++i)
      acc[i] = __builtin_amdgcn_mfma_f32_16x16x32_bf16(wfrag[i][kc], hf[kc],
                                                       acc[i], 0, 0, 0);
  __builtin_amdgcn_s_setprio(0);

  // 4) tanh; float4 global store; packed bf16 b64 -> other LDS buffer
#pragma unroll
  for (int i = 0; i < 2; ++i) {
    f32x4 h;
#pragma unroll
    for (int r = 0; r < 4; ++r) h[r] = tanh_fast(acc[i][r]);
    *reinterpret_cast<f32x4*>(&h_st[i][TOFF * RNN_H]) = h;
    if (last) *reinterpret_cast<f32x4*>(hl_st[i]) = h;

    unsigned p0, p1;
    asm("v_cvt_pk_bf16_f32 %0, %1, %2" : "=v"(p0) : "v"(h[0]), "v"(h[1]));
    asm("v_cvt_pk_bf16_f32 %0, %1, %2" : "=v"(p1) : "v"(h[2]), "v"(h[3]));
    uint2 pk; pk.x = p0; pk.y = p1;
    // batch=lrow, cols = (2*wid+i)*16 + lq*4 + {0..3}; byte = col*2 ^ swizzle
    const int byte = lrow * 512 + (((2 * wid + i) * 32 + lq * 8) ^ ((lrow & 7) << 4));
    *reinterpret_cast<uint2*>(&hb[RD ^ 1][byte >> 1]) = pk;
  }

  // 5) LDS-only barrier (global ops remain in flight)
  wg_barrier_lds_only();
}

// ---------------------------------------------------------------------------
// Kernel 2: MFMA recurrence. 4 WGs x 16 batches, 8 waves (512 thr) each.
// ---------------------------------------------------------------------------
__global__ __launch_bounds__(512, 2) void rnn_rec_mfma(
    const float* __restrict__ Wh, const float* __restrict__ h0, float* out,
    float* h_last) {
  __shared__ unsigned short hb[2][16 * 256];

  const int bg = blockIdx.x;
  const int tid = threadIdx.x;
  const int wid = tid >> 6;      // 0..7
  const int lane = tid & 63;
  const int lrow = lane & 15;    // batch (C cols) / A' m-index
  const int lq = lane >> 4;      // k-quad / C row-quad

  // ---- one-time: Wh^T A'-fragments (f32 -> bf16, RNE) into VGPRs -------
  // wfrag[i][kc][j] = Wh[kc*32 + lq*8 + j][(2*wid+i)*16 + lrow]
  bf16x8 wfrag[2][8];
#pragma unroll
  for (int i = 0; i < 2; ++i) {
    const int col = (wid * 2 + i) * 16 + lrow;
#pragma unroll
    for (int kc = 0; kc < 8; ++kc) {
      bf16x8 v;
#pragma unroll
      for (int j = 0; j < 8; ++j) {
        const int k = kc * 32 + lq * 8 + j;
        v[j] = (short)f32_to_bf16_rne(Wh[(size_t)k * RNN_H + col]);
      }
      wfrag[i][kc] = v;
    }
  }

  // ---- one-time: h0 -> hb[0] (bf16, swizzled) --------------------------
  {
    const int b = tid >> 5;            // 0..15
    const int c0 = (tid & 31) * 8;     // 8 cols per thread
#pragma unroll
    for (int c = 0; c < 8; ++c) {
      const float v = h0[(size_t)(bg * 16 + b) * RNN_H + c0 + c];
      hb[0][hidx(b, c0 + c)] = f32_to_bf16_rne(v);
    }
  }

  // per-lane global pointers: batch = lrow, 4 consecutive cols per tile
  float* outb = out + (size_t)bg * 16 * RNN_T * RNN_H;
  const float* xp_ld[2];
  float* h_st[2];
  float* hl_st[2];
  f32x4 xA[2], xB[2];
#pragma unroll
  for (int i = 0; i < 2; ++i) {
    const int col0 = (2 * wid + i) * 16 + lq * 4;
    float* hbase = outb + (size_t)lrow * RNN_T * RNN_H + col0;
    xp_ld[i] = hbase + RNN_H;  // -> xp[t=1]
    h_st[i] = hbase;           // -> h[t=0]
    hl_st[i] = h_last + (size_t)(bg * 16 + lrow) * RNN_H + col0;
    xA[i] = *reinterpret_cast<const f32x4*>(hbase);  // xp[t=0]
  }

  wg_barrier_lds_only();  // h0 staging visible

#pragma unroll 1
  for (int t = 0; t < RNN_T; t += 2) {
    const bool lastp = (t == RNN_T - 2);
    rnn_step<0, 0>(hb, wfrag, xA, xB, xp_ld, h_st, hl_st, false, lrow, lq, wid);
    rnn_step<1, 1>(hb, wfrag, xB, xA, xp_ld, h_st, hl_st, lastp, lrow, lq, wid);
#pragma unroll
    for (int i = 0; i < 2; ++i) {
      xp_ld[i] += 2 * RNN_H;
      h_st[i] += 2 * RNN_H;
    }
  }
}

extern "C" void kernel_launch(void* const* d_in, const int* in_sizes, int n_in,
                              void* d_out, int out_size, void* d_ws, size_t ws_size,
                              hipStream_t stream) {
  const float* x = (const float*)d_in[0];
  const float* h0 = (const float*)d_in[1];
  const float* Wx = (const float*)d_in[2];
  const float* Wh = (const float*)d_in[3];
  const float* bias = (const float*)d_in[4];
  float* out = (float*)d_out;
  float* h_last = out + (size_t)RNN_B * RNN_T * RNN_H;

  xp_gemm_kernel<<<RNN_B * RNN_T / 8, 256, 0, stream>>>(x, Wx, bias, out);
  rnn_rec_mfma<<<RNN_B / 16, 512, 0, stream>>>(Wh, h0, out, h_last);
}

// Round 6
// 1022.931 us; speedup vs baseline: 1.1155x; 1.1155x over previous
//
#include <hip/hip_runtime.h>

#define RNN_B 64
#define RNN_T 1024
#define RNN_D 256
#define RNN_H 256
#define NB 8  // batches per workgroup

typedef __attribute__((ext_vector_type(8))) short bf16x8;
typedef __attribute__((ext_vector_type(4))) float f32x4;

__device__ __forceinline__ unsigned short f32_to_bf16_rne(float f) {
  unsigned u = __builtin_bit_cast(unsigned, f);
  u += 0x7fffu + ((u >> 16) & 1u);
  return (unsigned short)(u >> 16);
}

// branch-free tanh: 1 - 2/(exp(2x)+1); exact at +/-inf, ~1e-6 abs err
__device__ __forceinline__ float tanh_fast(float x) {
  const float t = __expf(2.0f * x);
  const float r = __builtin_amdgcn_rcpf(t + 1.0f);
  return fmaf(-2.0f, r, 1.0f);
}

// swizzled u16 index of h[batch][col]; row stride 512B, XOR spreads rows
// across 16B bank-slots.
__device__ __forceinline__ int hidx(int batch, int col) {
  return ((batch & 7) * 512 + ((col * 2) ^ ((batch & 7) << 4))) >> 1;
}

__device__ __forceinline__ void wg_barrier_lds_only() {
  // drain LDS ops only; deliberately NOT vmcnt -> global xp prefetch and h
  // stores stay in flight across steps (avoids __syncthreads' vmcnt(0) drain)
  asm volatile("s_waitcnt lgkmcnt(0)" ::: "memory");
  __builtin_amdgcn_sched_barrier(0);
  __builtin_amdgcn_s_barrier();
  __builtin_amdgcn_sched_barrier(0);
}

// ---------------------------------------------------------------------------
// Kernel 1: xp[b,t,:] = x[b,t,:] @ Wx + b  (into the hs region of out) — f32
// ---------------------------------------------------------------------------
__global__ __launch_bounds__(256) void xp_gemm_kernel(
    const float* __restrict__ x, const float* __restrict__ Wx,
    const float* __restrict__ bias, float* __restrict__ xp) {
  __shared__ float xs[8][RNN_D];
  const int j = threadIdx.x;
  const size_t row0 = (size_t)blockIdx.x * 8;

  const float4* xg = reinterpret_cast<const float4*>(x + row0 * RNN_D);
  float4* xsv = reinterpret_cast<float4*>(&xs[0][0]);
  xsv[j] = xg[j];
  xsv[j + 256] = xg[j + 256];
  __syncthreads();

  const float bj = bias[j];
  float acc[8];
#pragma unroll
  for (int r = 0; r < 8; ++r) acc[r] = bj;

  for (int k = 0; k < RNN_D; k += 4) {
    const float w0 = Wx[(size_t)(k + 0) * RNN_H + j];
    const float w1 = Wx[(size_t)(k + 1) * RNN_H + j];
    const float w2 = Wx[(size_t)(k + 2) * RNN_H + j];
    const float w3 = Wx[(size_t)(k + 3) * RNN_H + j];
#pragma unroll
    for (int r = 0; r < 8; ++r) {
      const float4 xv = *reinterpret_cast<const float4*>(&xs[r][k]);
      acc[r] = fmaf(xv.x, w0, acc[r]);
      acc[r] = fmaf(xv.y, w1, acc[r]);
      acc[r] = fmaf(xv.z, w2, acc[r]);
      acc[r] = fmaf(xv.w, w3, acc[r]);
    }
  }
#pragma unroll
  for (int r = 0; r < 8; ++r) xp[(row0 + r) * RNN_H + j] = acc[r];
}

// ---------------------------------------------------------------------------
// One recurrence step. Swapped-operand MFMA: S^T = Wh^T (A') x h^T (B').
// 8 waves; wave wid owns outcol tiles nt = 2*wid + i (i in {0,1}).
// Only NB=8 batch columns are real: lanes with lrow >= NB are exec-masked
// off all LDS reads / global ld/st (their MFMA output cols are garbage,
// never stored). Masked lanes issue no LDS bank requests -> half pipe time.
//   A'-frag (Wh^T): m = lane&15 -> outcol; k = (lane>>4)*8+j   (VGPRs)
//   B'-frag (h^T):  n = lane&15 -> batch;  k likewise          (LDS b128)
//   C/D:            batch = lane&15, outcol = 16*nt + (lane>>4)*4 + r
// acc seeded with xp (C-in); even/odd kc chains halve MFMA dep depth.
// ---------------------------------------------------------------------------
template <int RD, int TOFF>
__device__ __forceinline__ void rnn_step(
    unsigned short (&hb)[2][NB * 256], const bf16x8 (&wfrag)[2][8],
    f32x4 (&xc)[2], f32x4 (&xn)[2],
    const float* const (&xp_ld)[2], float* const (&h_st)[2],
    float* const (&hl_st)[2], bool last, bool act, int lrow, int lq, int wid) {
  // 1) B'-fragments of h from LDS first (critical path), masked to NB rows
  bf16x8 hf[8];
  if (act) {
#pragma unroll
    for (int kc = 0; kc < 8; ++kc) {
      const int off = (lrow * 512 + ((kc * 64 + lq * 16) ^ (lrow << 4))) >> 1;
      hf[kc] = *reinterpret_cast<const bf16x8*>(&hb[RD][off]);
    }
  }

  // 2) prefetch xp for the NEXT step (consumed after the next barrier)
  if (act) {
#pragma unroll
    for (int i = 0; i < 2; ++i)
      xn[i] = *reinterpret_cast<const f32x4*>(&xp_ld[i][TOFF * RNN_H]);
  }

  // 3) MFMA: two independent chains per tile (even/odd kc), depth 4
  f32x4 accE[2] = {xc[0], xc[1]};
  f32x4 accO[2] = {{0.f, 0.f, 0.f, 0.f}, {0.f, 0.f, 0.f, 0.f}};
  __builtin_amdgcn_s_setprio(1);
#pragma unroll
  for (int kc = 0; kc < 8; kc += 2) {
#pragma unroll
    for (int i = 0; i < 2; ++i) {
      accE[i] = __builtin_amdgcn_mfma_f32_16x16x32_bf16(wfrag[i][kc], hf[kc],
                                                        accE[i], 0, 0, 0);
      accO[i] = __builtin_amdgcn_mfma_f32_16x16x32_bf16(wfrag[i][kc + 1],
                                                        hf[kc + 1], accO[i], 0,
                                                        0, 0);
    }
  }
  __builtin_amdgcn_s_setprio(0);

  // 4) tanh; float4 global store; packed bf16 b64 -> other LDS buffer
#pragma unroll
  for (int i = 0; i < 2; ++i) {
    f32x4 h;
#pragma unroll
    for (int r = 0; r < 4; ++r) h[r] = tanh_fast(accE[i][r] + accO[i][r]);
    if (act) {
      *reinterpret_cast<f32x4*>(&h_st[i][TOFF * RNN_H]) = h;
      if (last) *reinterpret_cast<f32x4*>(hl_st[i]) = h;

      unsigned p0, p1;
      asm("v_cvt_pk_bf16_f32 %0, %1, %2" : "=v"(p0) : "v"(h[0]), "v"(h[1]));
      asm("v_cvt_pk_bf16_f32 %0, %1, %2" : "=v"(p1) : "v"(h[2]), "v"(h[3]));
      uint2 pk; pk.x = p0; pk.y = p1;
      const int byte =
          lrow * 512 + (((2 * wid + i) * 32 + lq * 8) ^ (lrow << 4));
      *reinterpret_cast<uint2*>(&hb[RD ^ 1][byte >> 1]) = pk;
    }
  }

  // 5) LDS-only barrier (global ops remain in flight)
  wg_barrier_lds_only();
}

// ---------------------------------------------------------------------------
// Kernel 2: MFMA recurrence. 8 WGs x 8 batches, 8 waves (512 thr) each.
// ---------------------------------------------------------------------------
__global__ __launch_bounds__(512, 2) void rnn_rec_mfma(
    const float* __restrict__ Wh, const float* __restrict__ h0, float* out,
    float* h_last) {
  __shared__ unsigned short hb[2][NB * 256];

  const int bg = blockIdx.x;     // batch group 0..7
  const int tid = threadIdx.x;
  const int wid = tid >> 6;      // 0..7
  const int lane = tid & 63;
  const int lrow = lane & 15;    // batch (if < NB) / A' m-index
  const int lq = lane >> 4;      // k-quad / C row-quad
  const bool act = lrow < NB;

  // ---- one-time: Wh^T A'-fragments (f32 -> bf16, RNE) into VGPRs -------
  bf16x8 wfrag[2][8];
#pragma unroll
  for (int i = 0; i < 2; ++i) {
    const int col = (wid * 2 + i) * 16 + lrow;
#pragma unroll
    for (int kc = 0; kc < 8; ++kc) {
      bf16x8 v;
#pragma unroll
      for (int j = 0; j < 8; ++j) {
        const int k = kc * 32 + lq * 8 + j;
        v[j] = (short)f32_to_bf16_rne(Wh[(size_t)k * RNN_H + col]);
      }
      wfrag[i][kc] = v;
    }
  }

  // ---- one-time: h0 -> hb[0] (bf16, swizzled); 8 rows x 256 cols -------
  {
    const int b = tid >> 6;            // 0..7
    const int c0 = (tid & 63) * 4;     // 4 cols per thread
#pragma unroll
    for (int c = 0; c < 4; ++c) {
      const float v = h0[(size_t)(bg * NB + b) * RNN_H + c0 + c];
      hb[0][hidx(b, c0 + c)] = f32_to_bf16_rne(v);
    }
  }

  // per-lane global pointers: batch = lrow (if act), 4 consecutive cols/tile
  float* outb = out + (size_t)bg * NB * RNN_T * RNN_H;
  const float* xp_ld[2];
  float* h_st[2];
  float* hl_st[2];
  f32x4 xA[2], xB[2];
#pragma unroll
  for (int i = 0; i < 2; ++i) {
    const int col0 = (2 * wid + i) * 16 + lq * 4;
    float* hbase = outb + (size_t)(lrow & 7) * RNN_T * RNN_H + col0;
    xp_ld[i] = hbase + RNN_H;  // -> xp[t=1]
    h_st[i] = hbase;           // -> h[t=0]
    hl_st[i] = h_last + (size_t)(bg * NB + (lrow & 7)) * RNN_H + col0;
    if (act) xA[i] = *reinterpret_cast<const f32x4*>(hbase);  // xp[t=0]
  }

  wg_barrier_lds_only();  // h0 staging visible

#pragma unroll 1
  for (int t = 0; t < RNN_T; t += 2) {
    const bool lastp = (t == RNN_T - 2);
    rnn_step<0, 0>(hb, wfrag, xA, xB, xp_ld, h_st, hl_st, false, act, lrow, lq,
                   wid);
    rnn_step<1, 1>(hb, wfrag, xB, xA, xp_ld, h_st, hl_st, lastp, act, lrow, lq,
                   wid);
#pragma unroll
    for (int i = 0; i < 2; ++i) {
      xp_ld[i] += 2 * RNN_H;
      h_st[i] += 2 * RNN_H;
    }
  }
}

extern "C" void kernel_launch(void* const* d_in, const int* in_sizes, int n_in,
                              void* d_out, int out_size, void* d_ws, size_t ws_size,
                              hipStream_t stream) {
  const float* x = (const float*)d_in[0];
  const float* h0 = (const float*)d_in[1];
  const float* Wx = (const float*)d_in[2];
  const float* Wh = (const float*)d_in[3];
  const float* bias = (const float*)d_in[4];
  float* out = (float*)d_out;
  float* h_last = out + (size_t)RNN_B * RNN_T * RNN_H;

  xp_gemm_kernel<<<RNN_B * RNN_T / 8, 256, 0, stream>>>(x, Wx, bias, out);
  rnn_rec_mfma<<<RNN_B / NB, 512, 0, stream>>>(Wh, h0, out, h_last);
}

// Round 7
// 921.721 us; speedup vs baseline: 1.2380x; 1.1098x over previous
//
#include <hip/hip_runtime.h>

#define RNN_B 64
#define RNN_T 1024
#define RNN_D 256
#define RNN_H 256
#define NB 8  // batches per workgroup

typedef __attribute__((ext_vector_type(8))) short bf16x8;
typedef __attribute__((ext_vector_type(4))) float f32x4;

__device__ __forceinline__ unsigned short f32_to_bf16_rne(float f) {
  unsigned u = __builtin_bit_cast(unsigned, f);
  u += 0x7fffu + ((u >> 16) & 1u);
  return (unsigned short)(u >> 16);
}

// branch-free tanh: 1 - 2/(exp(2x)+1); exact at +/-inf, ~1e-6 abs err
__device__ __forceinline__ float tanh_fast(float x) {
  const float t = __expf(2.0f * x);
  const float r = __builtin_amdgcn_rcpf(t + 1.0f);
  return fmaf(-2.0f, r, 1.0f);
}

// swizzled u16 index of h[batch][col]; row stride 512B, XOR spreads rows
// across 16B bank-slots.
__device__ __forceinline__ int hidx(int batch, int col) {
  return ((batch & 7) * 512 + ((col * 2) ^ ((batch & 7) << 4))) >> 1;
}

__device__ __forceinline__ void wg_barrier_lds_only() {
  // drain LDS ops only; deliberately NOT vmcnt -> global xp prefetch and h
  // stores stay in flight across steps (avoids __syncthreads' vmcnt(0) drain)
  asm volatile("s_waitcnt lgkmcnt(0)" ::: "memory");
  __builtin_amdgcn_sched_barrier(0);
  __builtin_amdgcn_s_barrier();
  __builtin_amdgcn_sched_barrier(0);
}

// ---------------------------------------------------------------------------
// Kernel 1: xp[b,t,:] = x[b,t,:] @ Wx + b  (into the hs region of out) — f32
// ---------------------------------------------------------------------------
__global__ __launch_bounds__(256) void xp_gemm_kernel(
    const float* __restrict__ x, const float* __restrict__ Wx,
    const float* __restrict__ bias, float* __restrict__ xp) {
  __shared__ float xs[8][RNN_D];
  const int j = threadIdx.x;
  const size_t row0 = (size_t)blockIdx.x * 8;

  const float4* xg = reinterpret_cast<const float4*>(x + row0 * RNN_D);
  float4* xsv = reinterpret_cast<float4*>(&xs[0][0]);
  xsv[j] = xg[j];
  xsv[j + 256] = xg[j + 256];
  __syncthreads();

  const float bj = bias[j];
  float acc[8];
#pragma unroll
  for (int r = 0; r < 8; ++r) acc[r] = bj;

  for (int k = 0; k < RNN_D; k += 4) {
    const float w0 = Wx[(size_t)(k + 0) * RNN_H + j];
    const float w1 = Wx[(size_t)(k + 1) * RNN_H + j];
    const float w2 = Wx[(size_t)(k + 2) * RNN_H + j];
    const float w3 = Wx[(size_t)(k + 3) * RNN_H + j];
#pragma unroll
    for (int r = 0; r < 8; ++r) {
      const float4 xv = *reinterpret_cast<const float4*>(&xs[r][k]);
      acc[r] = fmaf(xv.x, w0, acc[r]);
      acc[r] = fmaf(xv.y, w1, acc[r]);
      acc[r] = fmaf(xv.z, w2, acc[r]);
      acc[r] = fmaf(xv.w, w3, acc[r]);
    }
  }
#pragma unroll
  for (int r = 0; r < 8; ++r) xp[(row0 + r) * RNN_H + j] = acc[r];
}

// ---------------------------------------------------------------------------
// One recurrence step. Swapped-operand MFMA: S^T = Wh^T (A') x h^T (B').
// 16 waves; wave wid owns ONE outcol tile (16 cols).
// Only NB=8 batch columns are real: lanes with lrow >= NB are exec-masked
// off LDS reads / global ld/st; their MFMA outputs are garbage, never stored.
//   A'-frag (Wh^T): m = lane&15 -> outcol; k = (lane>>4)*8+j   (VGPRs)
//   B'-frag (h^T):  n = lane&15 -> batch;  k likewise          (LDS b128)
//   C/D:            batch = lane&15, outcol = 16*wid + (lane>>4)*4 + r
// acc seeded with xp (C-in); even/odd kc chains halve MFMA dep depth.
// ---------------------------------------------------------------------------
template <int RD, int TOFF>
__device__ __forceinline__ void rnn_step(
    unsigned short (&hb)[2][NB * 256], const bf16x8 (&wfrag)[8],
    f32x4& xc, f32x4& xn, const float* xp_ld, float* h_st, float* hl_st,
    bool last, bool act, int lrow, int lq, int wid) {
  // 1) B'-fragments of h from LDS first (critical path), masked to NB rows
  bf16x8 hf[8];
  if (act) {
#pragma unroll
    for (int kc = 0; kc < 8; ++kc) {
      const int off = (lrow * 512 + ((kc * 64 + lq * 16) ^ (lrow << 4))) >> 1;
      hf[kc] = *reinterpret_cast<const bf16x8*>(&hb[RD][off]);
    }
    // 2) prefetch xp for the NEXT step (consumed after the next barrier)
    xn = *reinterpret_cast<const f32x4*>(&xp_ld[TOFF * RNN_H]);
  }

  // 3) MFMA: two independent chains (even/odd kc), depth 4
  f32x4 accE = xc;
  f32x4 accO = {0.f, 0.f, 0.f, 0.f};
  __builtin_amdgcn_s_setprio(1);
#pragma unroll
  for (int kc = 0; kc < 8; kc += 2) {
    accE = __builtin_amdgcn_mfma_f32_16x16x32_bf16(wfrag[kc], hf[kc], accE, 0,
                                                   0, 0);
    accO = __builtin_amdgcn_mfma_f32_16x16x32_bf16(wfrag[kc + 1], hf[kc + 1],
                                                   accO, 0, 0, 0);
  }
  __builtin_amdgcn_s_setprio(0);

  // 4) tanh; float4 global store; packed bf16 b64 -> other LDS buffer
  f32x4 h;
#pragma unroll
  for (int r = 0; r < 4; ++r) h[r] = tanh_fast(accE[r] + accO[r]);
  if (act) {
    *reinterpret_cast<f32x4*>(&h_st[TOFF * RNN_H]) = h;
    if (last) *reinterpret_cast<f32x4*>(hl_st) = h;

    unsigned p0, p1;
    asm("v_cvt_pk_bf16_f32 %0, %1, %2" : "=v"(p0) : "v"(h[0]), "v"(h[1]));
    asm("v_cvt_pk_bf16_f32 %0, %1, %2" : "=v"(p1) : "v"(h[2]), "v"(h[3]));
    uint2 pk; pk.x = p0; pk.y = p1;
    const int byte = lrow * 512 + ((wid * 32 + lq * 8) ^ (lrow << 4));
    *reinterpret_cast<uint2*>(&hb[RD ^ 1][byte >> 1]) = pk;
  }

  // 5) LDS-only barrier (global ops remain in flight)
  wg_barrier_lds_only();
}

// ---------------------------------------------------------------------------
// Kernel 2: MFMA recurrence. 8 WGs x 8 batches, 16 waves (1024 thr) each
// -> 4 waves/SIMD so chains cross-hide.
// ---------------------------------------------------------------------------
__global__ __launch_bounds__(1024, 4) void rnn_rec_mfma(
    const float* __restrict__ Wh, const float* __restrict__ h0, float* out,
    float* h_last) {
  __shared__ unsigned short hb[2][NB * 256];

  const int bg = blockIdx.x;     // batch group 0..7
  const int tid = threadIdx.x;
  const int wid = tid >> 6;      // 0..15 = outcol tile
  const int lane = tid & 63;
  const int lrow = lane & 15;    // batch (if < NB) / A' m-index
  const int lq = lane >> 4;      // k-quad / C row-quad
  const bool act = lrow < NB;

  // ---- one-time: Wh^T A'-fragments (f32 -> bf16, RNE) into VGPRs -------
  bf16x8 wfrag[8];
  {
    const int col = wid * 16 + lrow;
#pragma unroll
    for (int kc = 0; kc < 8; ++kc) {
      bf16x8 v;
#pragma unroll
      for (int j = 0; j < 8; ++j) {
        const int k = kc * 32 + lq * 8 + j;
        v[j] = (short)f32_to_bf16_rne(Wh[(size_t)k * RNN_H + col]);
      }
      wfrag[kc] = v;
    }
  }

  // ---- one-time: h0 -> hb[0] (bf16, swizzled); 8 rows x 256 cols -------
  {
    const int b = tid >> 7;            // 0..7
    const int c0 = (tid & 127) * 2;    // 2 cols per thread
    hb[0][hidx(b, c0 + 0)] =
        f32_to_bf16_rne(h0[(size_t)(bg * NB + b) * RNN_H + c0 + 0]);
    hb[0][hidx(b, c0 + 1)] =
        f32_to_bf16_rne(h0[(size_t)(bg * NB + b) * RNN_H + c0 + 1]);
  }

  // per-lane global pointers: batch = lrow (if act), 4 consecutive cols
  float* outb = out + (size_t)bg * NB * RNN_T * RNN_H;
  const int col0 = wid * 16 + lq * 4;
  float* hbase = outb + (size_t)(lrow & 7) * RNN_T * RNN_H + col0;
  const float* xp_ld = hbase + RNN_H;  // -> xp[t=1]
  float* h_st = hbase;                 // -> h[t=0]
  float* hl_st = h_last + (size_t)(bg * NB + (lrow & 7)) * RNN_H + col0;
  f32x4 xA, xB;
  if (act) xA = *reinterpret_cast<const f32x4*>(hbase);  // xp[t=0]

  wg_barrier_lds_only();  // h0 staging visible

#pragma unroll 1
  for (int t = 0; t < RNN_T; t += 2) {
    const bool lastp = (t == RNN_T - 2);
    rnn_step<0, 0>(hb, wfrag, xA, xB, xp_ld, h_st, hl_st, false, act, lrow, lq,
                   wid);
    rnn_step<1, 1>(hb, wfrag, xB, xA, xp_ld, h_st, hl_st, lastp, act, lrow, lq,
                   wid);
    xp_ld += 2 * RNN_H;
    h_st += 2 * RNN_H;
  }
}

extern "C" void kernel_launch(void* const* d_in, const int* in_sizes, int n_in,
                              void* d_out, int out_size, void* d_ws, size_t ws_size,
                              hipStream_t stream) {
  const float* x = (const float*)d_in[0];
  const float* h0 = (const float*)d_in[1];
  const float* Wx = (const float*)d_in[2];
  const float* Wh = (const float*)d_in[3];
  const float* bias = (const float*)d_in[4];
  float* out = (float*)d_out;
  float* h_last = out + (size_t)RNN_B * RNN_T * RNN_H;

  xp_gemm_kernel<<<RNN_B * RNN_T / 8, 256, 0, stream>>>(x, Wx, bias, out);
  rnn_rec_mfma<<<RNN_B / NB, 1024, 0, stream>>>(Wh, h0, out, h_last);
}